// Round 7
// baseline (1291.524 us; speedup 1.0000x reference)
//
#include <hip/hip_runtime.h>
#include <hip/hip_bf16.h>
#include <cstdint>

typedef __attribute__((ext_vector_type(2))) float f2;
typedef __attribute__((ext_vector_type(4))) float f4;
typedef __attribute__((ext_vector_type(4))) float f32x4;
typedef __attribute__((ext_vector_type(8))) __bf16 bf16x8;
typedef unsigned short ushort_t;
typedef unsigned int uint_t;

#define TTOK 2048
#define DDIM 2048
#define NEXP 64
#define TOPK 6
#define FDIM 1408
#define FSH  2816
#define NASSIGN (TTOK*TOPK)

#define SBAR()     __asm__ __volatile__("s_barrier" ::: "memory")
#define WAITVMC(N) __asm__ __volatile__("s_waitcnt vmcnt(" #N ")" ::: "memory")
#define WAITLG()   __asm__ __volatile__("s_waitcnt lgkmcnt(0)" ::: "memory")

// ---------- helpers ----------
__device__ __forceinline__ ushort_t f2bf(float f){
  uint_t u = __builtin_bit_cast(uint_t, f);
  u = (u + 0x7FFFu + ((u >> 16) & 1u)) >> 16;
  return (ushort_t)u;
}
__device__ __forceinline__ float bf2f(uint_t b){
  uint_t u = (b & 0xFFFFu) << 16;
  return __builtin_bit_cast(float, u);
}
__device__ __forceinline__ void gld_lds16(const void* g, void* l){
  __builtin_amdgcn_global_load_lds((const __attribute__((address_space(1))) uint_t*)g,
                                   (__attribute__((address_space(3))) uint_t*)l, 16, 0, 0);
}

// ---------- gate: logits + top-6 + renorm ----------
__global__ __launch_bounds__(256) void gate_topk_kernel(
    const float* __restrict__ x, const float* __restrict__ gw,
    int* __restrict__ topi, float* __restrict__ topw)
{
  __shared__ float xs[4*2048];
  __shared__ float lg[4*64];
  int tid = threadIdx.x;
  int t0 = blockIdx.x*4;
  const f4* xg = (const f4*)(x + (size_t)t0*DDIM);
  f4* xsv = (f4*)xs;
  for (int i = tid; i < 2048; i += 256) xsv[i] = xg[i];
  __syncthreads();
  int g = tid >> 6, l = tid & 63;
  int c = l & 3, er = l >> 2;
  const f4* xrow = (const f4*)(xs + g*2048 + c*512);
  #pragma unroll
  for (int eo = 0; eo < 4; ++eo){
    int e = eo*16 + er;
    const f4* wrow = (const f4*)(gw + (size_t)e*DDIM + c*512);
    float d = 0.f;
    #pragma unroll 4
    for (int j = 0; j < 128; ++j){
      f4 w = wrow[j], a = xrow[j];
      d += w.x*a.x + w.y*a.y + w.z*a.z + w.w*a.w;
    }
    d += __shfl_xor(d, 1);
    d += __shfl_xor(d, 2);
    if (c == 0) lg[g*64 + e] = d;
  }
  __syncthreads();
  float mv = lg[g*64 + l];
  float sv[6]; int si[6];
  #pragma unroll
  for (int s = 0; s < 6; ++s){
    float bv = mv; int bi = l;
    for (int off = 32; off > 0; off >>= 1){
      float ov = __shfl_xor(bv, off);
      int oi = __shfl_xor(bi, off);
      if (ov > bv || (ov == bv && oi < bi)){ bv = ov; bi = oi; }
    }
    sv[s] = bv; si[s] = bi;
    if (l == bi) mv = -3.4e38f;
  }
  if (l == 0){
    float sum = 0.f, wv[6];
    #pragma unroll
    for (int s = 0; s < 6; ++s){ wv[s] = __expf(sv[s] - sv[0]); sum += wv[s]; }
    float inv = 1.f/sum;
    int t = t0 + g;
    #pragma unroll
    for (int s = 0; s < 6; ++s){ topi[t*6+s] = si[s]; topw[t*6+s] = wv[s]*inv; }
  }
}

// ---------- x -> bf16 ----------
__global__ __launch_bounds__(256) void xcast_kernel(const float* __restrict__ x, ushort_t* __restrict__ xb){
  size_t base = ((size_t)blockIdx.x*256 + threadIdx.x)*8;
  f4 a = *(const f4*)(x + base);
  f4 b = *(const f4*)(x + base + 4);
  uint4 r;
  r.x = f2bf(a.x) | ((uint_t)f2bf(a.y)<<16);
  r.y = f2bf(a.z) | ((uint_t)f2bf(a.w)<<16);
  r.z = f2bf(b.x) | ((uint_t)f2bf(b.y)<<16);
  r.w = f2bf(b.z) | ((uint_t)f2bf(b.w)<<16);
  *(uint4*)(xb + base) = r;
}

// ---------- routing bookkeeping ----------
__global__ __launch_bounds__(256) void count_kernel(const int* __restrict__ topi, int* __restrict__ counts){
  int a = blockIdx.x*256 + threadIdx.x;
  if (a < NASSIGN) atomicAdd(&counts[topi[a]], 1);
}
__global__ void scan_kernel(const int* __restrict__ counts, int* __restrict__ offsets){
  if (threadIdx.x == 0){
    int s = 0;
    for (int e = 0; e < NEXP; ++e){ offsets[e] = s; s += counts[e]; }
    offsets[NEXP] = s;
  }
}
__global__ __launch_bounds__(256) void scatter_kernel(
    const int* __restrict__ topi, const float* __restrict__ topw,
    const int* __restrict__ offsets, int* __restrict__ cursor,
    int* __restrict__ row_token, float* __restrict__ row_w, int* __restrict__ row_assign)
{
  int a = blockIdx.x*256 + threadIdx.x;
  if (a < NASSIGN){
    int e = topi[a];
    int pos = atomicAdd(&cursor[e], 1);
    int r = offsets[e] + pos;
    row_token[r]  = a / 6;
    row_w[r]      = topw[a];
    row_assign[r] = a;
  }
}

// ============ GEMM core: BM=256 BN=64 BK=32, 512 thr (8 waves 4m x 2n, wave 64x32) ============
// ============ mfma 16x16x32 (verified layout), LDS ~37KB -> 4 blocks/CU, counted vmcnt ========
// gsrc==null: H = acc (bf16).  gsrc!=null: H = silu(gsrc)*acc (bf16).
__global__ __launch_bounds__(512, 4) void gemm_xw_kernel(
    const ushort_t* __restrict__ A, const float* __restrict__ B0,
    const ushort_t* __restrict__ gsrc, ushort_t* __restrict__ H,
    const int* __restrict__ offsets, const int* __restrict__ row_token,
    const ushort_t* __restrict__ zerop,
    int N, int K, int lda, int n_mt, int n_nt, int Mfix)
{
  int nwg = gridDim.x, chunk = nwg >> 3;
  int L = (blockIdx.x & 7)*chunk + (blockIdx.x >> 3);
  int e, mt, nt, row0, rowcnt;
  if (offsets){
    int per = n_mt*n_nt; e = L/per; int rem = L - e*per; mt = rem/n_nt; nt = rem - mt*n_nt;
    row0 = offsets[e]; rowcnt = offsets[e+1] - row0;
  } else { e = 0; nt = L/n_mt; mt = L - nt*n_mt; row0 = 0; rowcnt = Mfix; }
  int m0 = mt*256;
  if (m0 >= rowcnt) return;

  const float* B = B0 + (size_t)e*K*N + nt*64;

  __shared__ ushort_t As[2][8192];   // [buf][256r x 32k] 16KB each
  __shared__ ushort_t Bs[2048];      // [64n x 32k] 4KB

  int tid = threadIdx.x;
  int lane = tid & 63;
  int wid = tid >> 6;
  int wm = wid >> 1, wn = wid & 1;

  // A staging: 2 gld_lds16/thread; op i: row r=(tid>>2)+128i, lds slot tid&3 (linear),
  // source chunk pre-swizzled: sslot = (tid&3) ^ ((r>>1)&3)
  int sslot = (tid & 3) ^ ((tid >> 3) & 3);
  const ushort_t* asrc[2];
  #pragma unroll
  for (int i = 0; i < 2; ++i){
    int r = (tid >> 2) + i*128;
    int gr = m0 + r;
    bool v = gr < rowcnt;
    int tok = row_token ? (v ? row_token[row0+gr] : 0) : gr;
    const ushort_t* p = v ? (A + (size_t)tok*lda) : zerop;
    asrc[i] = p + sslot*8;
  }

  // B staging: thread (n2=tid&31 -> cols 2n2,2n2+1; k2=tid>>5 -> k rows 2k2,2k2+1)
  int n2 = tid & 31, k2 = tid >> 5;
  const float* bbase = B + (size_t)(k2*2)*N + n2*2;
  int bdoff[2];
  #pragma unroll
  for (int c = 0; c < 2; ++c){
    int n = n2*2 + c;
    int slot = ((k2 >> 2) ^ ((n >> 1) & 3)) & 3;
    bdoff[c] = n*32 + slot*8 + (k2 & 3)*2;
  }

  f32x4 acc[4][2];
  #pragma unroll
  for (int i=0;i<4;++i)
    #pragma unroll
    for (int j=0;j<2;++j) acc[i][j] = f32x4{0.f,0.f,0.f,0.f};

  int nK = K >> 5;
  // ---- prologue: B(0) reg loads first, A(0) gld_lds stays in flight across ds_write ----
  {
    f2 v0 = *(const f2*)(bbase);
    f2 v1 = *(const f2*)(bbase + (size_t)N);
    #pragma unroll
    for (int i = 0; i < 2; ++i)
      gld_lds16(asrc[i], &As[0][i*4096 + tid*8]);
    #pragma unroll
    for (int c = 0; c < 2; ++c){
      uint_t pk = f2bf(v0[c]) | ((uint_t)f2bf(v1[c]) << 16);
      *(uint_t*)&Bs[bdoff[c]] = pk;
    }
    WAITLG();
  }

  for (int ks = 0; ks < nK; ++ks){
    int cur = ks & 1, nxt = cur ^ 1;
    bool pf = (ks + 1) < nK;
    f2 v0, v1;
    if (pf){
      const float* bp = bbase + (size_t)((ks + 1) << 5)*N;
      v0 = *(const f2*)(bp);
      v1 = *(const f2*)(bp + (size_t)N);
      int k0n = (ks + 1) << 5;
      #pragma unroll
      for (int i = 0; i < 2; ++i)
        gld_lds16(asrc[i] + k0n, &As[nxt][i*4096 + tid*8]);
      WAITVMC(4);          // drain A(ks)[2]; keep B(ks+1)[2]+A(ks+1)[2]
    } else {
      WAITVMC(0);
    }
    SBAR();                // A(ks)/B(ks) ready

    {
      int kc = lane >> 4;                    // k-chunk 0..3 (8 bf16 each), K=32
      bf16x8 af[4], bb[2];
      #pragma unroll
      for (int i = 0; i < 4; ++i){
        int ar = wm*64 + i*16 + (lane & 15);
        int ch = (kc ^ ((ar >> 1) & 3)) & 3;
        af[i] = *(const bf16x8*)&As[cur][ar*32 + ch*8];
      }
      #pragma unroll
      for (int j = 0; j < 2; ++j){
        int br = wn*32 + j*16 + (lane & 15);
        int ch = (kc ^ ((br >> 1) & 3)) & 3;
        bb[j] = *(const bf16x8*)&Bs[br*32 + ch*8];
      }
      #pragma unroll
      for (int i = 0; i < 4; ++i)
        #pragma unroll
        for (int j = 0; j < 2; ++j)
          acc[i][j] = __builtin_amdgcn_mfma_f32_16x16x32_bf16(af[i], bb[j], acc[i][j], 0,0,0);
    }
    SBAR();                // all waves done reading Bs / As[cur]
    if (pf){
      #pragma unroll
      for (int c = 0; c < 2; ++c){
        uint_t pk = f2bf(v0[c]) | ((uint_t)f2bf(v1[c]) << 16);
        *(uint_t*)&Bs[bdoff[c]] = pk;   // auto vmcnt drains B(ks+1), keeps A(ks+1)
      }
      WAITLG();
    }
  }

  #pragma unroll
  for (int i = 0; i < 4; ++i)
    #pragma unroll
    for (int j = 0; j < 2; ++j){
      int col = nt*64 + wn*32 + j*16 + (lane & 15);
      #pragma unroll
      for (int q = 0; q < 4; ++q){
        int r = wm*64 + i*16 + ((lane >> 4) << 2) + q;
        int gr = m0 + r;
        if (gr < rowcnt){
          float val = acc[i][j][q];
          size_t idx = (size_t)(row0 + gr)*(size_t)N + col;
          if (gsrc){
            float g = bf2f(gsrc[idx]);
            val = (g / (1.f + __expf(-g))) * val;
          }
          H[idx] = f2bf(val);
        }
      }
    }
}

// ---------- down GEMM: same core; routed -> weighted bf16 rows; shared -> f32 out ----------
__global__ __launch_bounds__(512, 4) void gemm_down_kernel(
    const ushort_t* __restrict__ A, const float* __restrict__ B0,
    ushort_t* __restrict__ outb, float* __restrict__ outf,
    const int* __restrict__ offsets, const float* __restrict__ row_w, const int* __restrict__ row_assign,
    const ushort_t* __restrict__ zerop,
    int N, int K, int lda, int n_mt, int n_nt, int Mfix)
{
  int nwg = gridDim.x, chunk = nwg >> 3;
  int L = (blockIdx.x & 7)*chunk + (blockIdx.x >> 3);
  int e, mt, nt, row0, rowcnt;
  if (offsets){
    int per = n_mt*n_nt; e = L/per; int rem = L - e*per; mt = rem/n_nt; nt = rem - mt*n_nt;
    row0 = offsets[e]; rowcnt = offsets[e+1] - row0;
  } else { e = 0; nt = L/n_mt; mt = L - nt*n_mt; row0 = 0; rowcnt = Mfix; }
  int m0 = mt*256;
  if (m0 >= rowcnt) return;

  const float* B = B0 + (size_t)e*K*N + nt*64;

  __shared__ ushort_t As[2][8192];
  __shared__ ushort_t Bs[2048];
  __shared__ float Wr[256];
  __shared__ int Ar[256];

  int tid = threadIdx.x;
  int lane = tid & 63;
  int wid = tid >> 6;
  int wm = wid >> 1, wn = wid & 1;

  if (offsets && tid < 256){
    int gr = m0 + tid;
    bool v = gr < rowcnt;
    Wr[tid] = v ? row_w[row0+gr] : 0.f;
    Ar[tid] = v ? row_assign[row0+gr] : 0;
  }

  int sslot = (tid & 3) ^ ((tid >> 3) & 3);
  const ushort_t* asrc[2];
  #pragma unroll
  for (int i = 0; i < 2; ++i){
    int r = (tid >> 2) + i*128;
    int gr = m0 + r;
    bool v = gr < rowcnt;
    const ushort_t* p = v ? (A + (size_t)(row0+gr)*lda) : zerop;
    asrc[i] = p + sslot*8;
  }

  int n2 = tid & 31, k2 = tid >> 5;
  const float* bbase = B + (size_t)(k2*2)*N + n2*2;
  int bdoff[2];
  #pragma unroll
  for (int c = 0; c < 2; ++c){
    int n = n2*2 + c;
    int slot = ((k2 >> 2) ^ ((n >> 1) & 3)) & 3;
    bdoff[c] = n*32 + slot*8 + (k2 & 3)*2;
  }

  f32x4 acc[4][2];
  #pragma unroll
  for (int i=0;i<4;++i)
    #pragma unroll
    for (int j=0;j<2;++j) acc[i][j] = f32x4{0.f,0.f,0.f,0.f};

  int nK = K >> 5;
  {
    f2 v0 = *(const f2*)(bbase);
    f2 v1 = *(const f2*)(bbase + (size_t)N);
    #pragma unroll
    for (int i = 0; i < 2; ++i)
      gld_lds16(asrc[i], &As[0][i*4096 + tid*8]);
    #pragma unroll
    for (int c = 0; c < 2; ++c){
      uint_t pk = f2bf(v0[c]) | ((uint_t)f2bf(v1[c]) << 16);
      *(uint_t*)&Bs[bdoff[c]] = pk;
    }
    WAITLG();
  }

  for (int ks = 0; ks < nK; ++ks){
    int cur = ks & 1, nxt = cur ^ 1;
    bool pf = (ks + 1) < nK;
    f2 v0, v1;
    if (pf){
      const float* bp = bbase + (size_t)((ks + 1) << 5)*N;
      v0 = *(const f2*)(bp);
      v1 = *(const f2*)(bp + (size_t)N);
      int k0n = (ks + 1) << 5;
      #pragma unroll
      for (int i = 0; i < 2; ++i)
        gld_lds16(asrc[i] + k0n, &As[nxt][i*4096 + tid*8]);
      WAITVMC(4);
    } else {
      WAITVMC(0);
    }
    SBAR();

    {
      int kc = lane >> 4;
      bf16x8 af[4], bb[2];
      #pragma unroll
      for (int i = 0; i < 4; ++i){
        int ar = wm*64 + i*16 + (lane & 15);
        int ch = (kc ^ ((ar >> 1) & 3)) & 3;
        af[i] = *(const bf16x8*)&As[cur][ar*32 + ch*8];
      }
      #pragma unroll
      for (int j = 0; j < 2; ++j){
        int br = wn*32 + j*16 + (lane & 15);
        int ch = (kc ^ ((br >> 1) & 3)) & 3;
        bb[j] = *(const bf16x8*)&Bs[br*32 + ch*8];
      }
      #pragma unroll
      for (int i = 0; i < 4; ++i)
        #pragma unroll
        for (int j = 0; j < 2; ++j)
          acc[i][j] = __builtin_amdgcn_mfma_f32_16x16x32_bf16(af[i], bb[j], acc[i][j], 0,0,0);
    }
    SBAR();
    if (pf){
      #pragma unroll
      for (int c = 0; c < 2; ++c){
        uint_t pk = f2bf(v0[c]) | ((uint_t)f2bf(v1[c]) << 16);
        *(uint_t*)&Bs[bdoff[c]] = pk;
      }
      WAITLG();
    }
  }

  #pragma unroll
  for (int i = 0; i < 4; ++i)
    #pragma unroll
    for (int j = 0; j < 2; ++j){
      int col = nt*64 + wn*32 + j*16 + (lane & 15);
      #pragma unroll
      for (int q = 0; q < 4; ++q){
        int r = wm*64 + i*16 + ((lane >> 4) << 2) + q;
        int gr = m0 + r;
        if (gr < rowcnt){
          float val = acc[i][j][q];
          if (offsets){
            outb[(size_t)Ar[r]*2048 + col] = f2bf(val * Wr[r]);
          } else {
            outf[(size_t)gr*2048 + col] = val;
          }
        }
      }
    }
}

// ---------- combine: out += sum_k out_assign[t*6+k] ----------
__global__ __launch_bounds__(256) void combine_kernel(const ushort_t* __restrict__ oa, float* __restrict__ out){
  size_t base = ((size_t)blockIdx.x*256 + threadIdx.x)*8;
  int t = (int)(base >> 11);
  int d = (int)(base & 2047);
  f4 s0 = *(const f4*)(out + base);
  f4 s1 = *(const f4*)(out + base + 4);
  #pragma unroll
  for (int k = 0; k < 6; ++k){
    const ushort_t* row = oa + (((size_t)(t*6+k)) << 11) + d;
    uint4 u = *(const uint4*)row;
    s0.x += bf2f(u.x); s0.y += bf2f(u.x >> 16);
    s0.z += bf2f(u.y); s0.w += bf2f(u.y >> 16);
    s1.x += bf2f(u.z); s1.y += bf2f(u.z >> 16);
    s1.z += bf2f(u.w); s1.w += bf2f(u.w >> 16);
  }
  *(f4*)(out + base) = s0;
  *(f4*)(out + base + 4) = s1;
}

extern "C" void kernel_launch(void* const* d_in, const int* in_sizes, int n_in,
                              void* d_out, int out_size, void* d_ws, size_t ws_size,
                              hipStream_t stream)
{
  const float* x       = (const float*)d_in[0];
  const float* gate_w  = (const float*)d_in[1];
  const float* w_gate  = (const float*)d_in[2];
  const float* w_up    = (const float*)d_in[3];
  const float* w_down  = (const float*)d_in[4];
  const float* ws_gate = (const float*)d_in[5];
  const float* ws_up   = (const float*)d_in[6];
  const float* ws_down = (const float*)d_in[7];
  float* out = (float*)d_out;

  char* ws = (char*)d_ws;
  int*      topi       = (int*)(ws + 0);           // 49152
  float*    topw       = (float*)(ws + 49152);     // 49152
  int*      counts     = (int*)(ws + 98304);       // 256
  int*      cursor     = (int*)(ws + 98560);       // 256
  int*      offsets    = (int*)(ws + 98816);       // 512
  int*      row_token  = (int*)(ws + 99328);       // 49152
  float*    row_w      = (float*)(ws + 148480);    // 49152
  int*      row_assign = (int*)(ws + 197632);      // 49152
  ushort_t* zerop      = (ushort_t*)(ws + 262144); // 8192B zeros
  ushort_t* xb         = (ushort_t*)(ws + 524288);   // 8.39 MB
  ushort_t* Hbuf       = (ushort_t*)(ws + 8912896);  // 34.6 MB  [12288 x 1408] bf16
  ushort_t* Shbuf      = (ushort_t*)(ws + 43515904); // 11.5 MB  [2048 x 2816] bf16
  ushort_t* oa         = (ushort_t*)(ws + 55050240); // 50.3 MB  [12288 x 2048] bf16
  // G buffers alias oa (dead before routed-down writes oa)
  ushort_t* Gbuf = oa;                                          // 34.6 MB [12288 x 1408]
  ushort_t* GS   = (ushort_t*)(ws + 55050240 + 34603008);       // 11.5 MB [2048 x 2816]
  (void)ws_size; (void)in_sizes; (void)n_in; (void)out_size;

  hipMemsetAsync(ws + 98304, 0, 512, stream);     // counts + cursor
  hipMemsetAsync(zerop, 0, 8192, stream);

  gate_topk_kernel<<<512, 256, 0, stream>>>(x, gate_w, topi, topw);
  xcast_kernel<<<2048, 256, 0, stream>>>(x, xb);
  count_kernel<<<48, 256, 0, stream>>>(topi, counts);
  scan_kernel<<<1, 64, 0, stream>>>(counts, offsets);
  scatter_kernel<<<48, 256, 0, stream>>>(topi, topw, offsets, cursor, row_token, row_w, row_assign);

  // routed gate: 64e x 2mt x 22nt -> Gbuf
  gemm_xw_kernel<<<2816, 512, 0, stream>>>(xb, w_gate, nullptr, Gbuf, offsets, row_token, zerop,
                                           FDIM, DDIM, DDIM, 2, 22, 0);
  // shared gate: 8mt x 44nt -> GS
  gemm_xw_kernel<<<352, 512, 0, stream>>>(xb, ws_gate, nullptr, GS, nullptr, nullptr, zerop,
                                          FSH, DDIM, DDIM, 8, 44, TTOK);
  // routed up (+silu combine): -> Hbuf
  gemm_xw_kernel<<<2816, 512, 0, stream>>>(xb, w_up, Gbuf, Hbuf, offsets, row_token, zerop,
                                           FDIM, DDIM, DDIM, 2, 22, 0);
  // shared up (+silu combine): -> Shbuf
  gemm_xw_kernel<<<352, 512, 0, stream>>>(xb, ws_up, GS, Shbuf, nullptr, nullptr, zerop,
                                          FSH, DDIM, DDIM, 8, 44, TTOK);
  // shared down -> d_out (f32)
  gemm_down_kernel<<<256, 512, 0, stream>>>(Shbuf, ws_down, nullptr, out, nullptr, nullptr, nullptr, zerop,
                                            DDIM, FSH, FSH, 8, 32, TTOK);
  // routed down -> weighted bf16 per-assignment rows (overwrites dead G region)
  gemm_down_kernel<<<4096, 512, 0, stream>>>(Hbuf, w_down, oa, nullptr, offsets, row_w, row_assign, zerop,
                                             DDIM, FDIM, FDIM, 2, 32, 0);
  // combine: out += sum of 6 assignment rows
  combine_kernel<<<2048, 256, 0, stream>>>(oa, out);
}

// Round 8
// 1236.562 us; speedup vs baseline: 1.0444x; 1.0444x over previous
//
#include <hip/hip_runtime.h>
#include <hip/hip_bf16.h>
#include <cstdint>

typedef __attribute__((ext_vector_type(2))) float f2;
typedef __attribute__((ext_vector_type(4))) float f4;
typedef __attribute__((ext_vector_type(4))) float f32x4;
typedef __attribute__((ext_vector_type(8))) __bf16 bf16x8;
typedef unsigned short ushort_t;
typedef unsigned int uint_t;

#define TTOK 2048
#define DDIM 2048
#define NEXP 64
#define TOPK 6
#define FDIM 1408
#define FSH  2816
#define NASSIGN (TTOK*TOPK)

#define SBAR()     __asm__ __volatile__("s_barrier" ::: "memory")
#define WAITVMC(N) __asm__ __volatile__("s_waitcnt vmcnt(" #N ")" ::: "memory")
#define WAITLG()   __asm__ __volatile__("s_waitcnt lgkmcnt(0)" ::: "memory")

// ---------- helpers ----------
__device__ __forceinline__ ushort_t f2bf(float f){
  uint_t u = __builtin_bit_cast(uint_t, f);
  u = (u + 0x7FFFu + ((u >> 16) & 1u)) >> 16;
  return (ushort_t)u;
}
__device__ __forceinline__ float bf2f(uint_t b){
  uint_t u = (b & 0xFFFFu) << 16;
  return __builtin_bit_cast(float, u);
}
__device__ __forceinline__ void gld_lds16(const void* g, void* l){
  __builtin_amdgcn_global_load_lds((const __attribute__((address_space(1))) uint_t*)g,
                                   (__attribute__((address_space(3))) uint_t*)l, 16, 0, 0);
}

// ---------- gate: logits + top-6 + renorm ----------
__global__ __launch_bounds__(256) void gate_topk_kernel(
    const float* __restrict__ x, const float* __restrict__ gw,
    int* __restrict__ topi, float* __restrict__ topw)
{
  __shared__ float xs[4*2048];
  __shared__ float lg[4*64];
  int tid = threadIdx.x;
  int t0 = blockIdx.x*4;
  const f4* xg = (const f4*)(x + (size_t)t0*DDIM);
  f4* xsv = (f4*)xs;
  for (int i = tid; i < 2048; i += 256) xsv[i] = xg[i];
  __syncthreads();
  int g = tid >> 6, l = tid & 63;
  int c = l & 3, er = l >> 2;
  const f4* xrow = (const f4*)(xs + g*2048 + c*512);
  #pragma unroll
  for (int eo = 0; eo < 4; ++eo){
    int e = eo*16 + er;
    const f4* wrow = (const f4*)(gw + (size_t)e*DDIM + c*512);
    float d = 0.f;
    #pragma unroll 4
    for (int j = 0; j < 128; ++j){
      f4 w = wrow[j], a = xrow[j];
      d += w.x*a.x + w.y*a.y + w.z*a.z + w.w*a.w;
    }
    d += __shfl_xor(d, 1);
    d += __shfl_xor(d, 2);
    if (c == 0) lg[g*64 + e] = d;
  }
  __syncthreads();
  float mv = lg[g*64 + l];
  float sv[6]; int si[6];
  #pragma unroll
  for (int s = 0; s < 6; ++s){
    float bv = mv; int bi = l;
    for (int off = 32; off > 0; off >>= 1){
      float ov = __shfl_xor(bv, off);
      int oi = __shfl_xor(bi, off);
      if (ov > bv || (ov == bv && oi < bi)){ bv = ov; bi = oi; }
    }
    sv[s] = bv; si[s] = bi;
    if (l == bi) mv = -3.4e38f;
  }
  if (l == 0){
    float sum = 0.f, wv[6];
    #pragma unroll
    for (int s = 0; s < 6; ++s){ wv[s] = __expf(sv[s] - sv[0]); sum += wv[s]; }
    float inv = 1.f/sum;
    int t = t0 + g;
    #pragma unroll
    for (int s = 0; s < 6; ++s){ topi[t*6+s] = si[s]; topw[t*6+s] = wv[s]*inv; }
  }
}

// ---------- x -> bf16 ----------
__global__ __launch_bounds__(256) void xcast_kernel(const float* __restrict__ x, ushort_t* __restrict__ xb){
  size_t base = ((size_t)blockIdx.x*256 + threadIdx.x)*8;
  f4 a = *(const f4*)(x + base);
  f4 b = *(const f4*)(x + base + 4);
  uint4 r;
  r.x = f2bf(a.x) | ((uint_t)f2bf(a.y)<<16);
  r.y = f2bf(a.z) | ((uint_t)f2bf(a.w)<<16);
  r.z = f2bf(b.x) | ((uint_t)f2bf(b.y)<<16);
  r.w = f2bf(b.z) | ((uint_t)f2bf(b.w)<<16);
  *(uint4*)(xb + base) = r;
}

// ---------- routing bookkeeping ----------
__global__ __launch_bounds__(256) void count_kernel(const int* __restrict__ topi, int* __restrict__ counts){
  int a = blockIdx.x*256 + threadIdx.x;
  if (a < NASSIGN) atomicAdd(&counts[topi[a]], 1);
}
__global__ void scan_kernel(const int* __restrict__ counts, int* __restrict__ offsets){
  if (threadIdx.x == 0){
    int s = 0;
    for (int e = 0; e < NEXP; ++e){ offsets[e] = s; s += counts[e]; }
    offsets[NEXP] = s;
  }
}
__global__ __launch_bounds__(256) void scatter_kernel(
    const int* __restrict__ topi, const float* __restrict__ topw,
    const int* __restrict__ offsets, int* __restrict__ cursor,
    int* __restrict__ row_token, float* __restrict__ row_w, int* __restrict__ row_assign)
{
  int a = blockIdx.x*256 + threadIdx.x;
  if (a < NASSIGN){
    int e = topi[a];
    int pos = atomicAdd(&cursor[e], 1);
    int r = offsets[e] + pos;
    row_token[r]  = a / 6;
    row_w[r]      = topw[a];
    row_assign[r] = a;
  }
}

// ======= GEMM core: BM=256 BN=64 BK=32, 512 thr (8 waves 4m x 2n), mfma 16x16x32 =======
// 1 barrier/step; A via gld_lds 2-steps-ahead (4 bufs); B reg-staged 1-step-ahead (2 reg
// sets + 2 LDS bufs); counted vmcnt(4) never drains in steady state. LDS ~74KB -> 2 blk/CU.

// one K-step; J = compile-time step-in-group (0..3). RBW = regs holding B(t+1) (to write),
// RBL = regs to load B(t+2) into.
#define GEMM_STEP(J, RBW0, RBW1, RBL0, RBL1)                                     \
  {                                                                              \
    const int t_ = base + (J);                                                   \
    if (t_ + 2 < nK) { WAITVMC(4); } else { WAITVMC(0); }                        \
    WAITLG();                                                                    \
    SBAR();                                                                      \
    if (t_ + 1 < nK) {                                                           \
      uint_t pk0 = f2bf(RBW0[0]) | ((uint_t)f2bf(RBW1[0]) << 16);                \
      uint_t pk1 = f2bf(RBW0[1]) | ((uint_t)f2bf(RBW1[1]) << 16);                \
      *(uint_t*)&Bs[((J)+1)&1][bdoff0] = pk0;                                    \
      *(uint_t*)&Bs[((J)+1)&1][bdoff1] = pk1;                                    \
    }                                                                            \
    if (t_ + 2 < nK) {                                                           \
      const float* bp_ = bbase + (size_t)((t_ + 2) << 5) * N;                    \
      RBL0 = *(const f2*)(bp_);                                                  \
      RBL1 = *(const f2*)(bp_ + (size_t)N);                                      \
      int k0n_ = (t_ + 2) << 5;                                                  \
      gld_lds16(asrc0 + k0n_, &As[((J)+2)&3][tid*8]);                            \
      gld_lds16(asrc1 + k0n_, &As[((J)+2)&3][4096 + tid*8]);                     \
    }                                                                            \
    {                                                                            \
      int kc = lane >> 4;                                                        \
      bf16x8 af[4], bb[2];                                                       \
      _Pragma("unroll")                                                          \
      for (int i_ = 0; i_ < 4; ++i_){                                            \
        int ar = wm*64 + i_*16 + (lane & 15);                                    \
        int ch = (kc ^ ((ar >> 1) & 3)) & 3;                                     \
        af[i_] = *(const bf16x8*)&As[(J)&3][ar*32 + ch*8];                       \
      }                                                                          \
      _Pragma("unroll")                                                          \
      for (int j_ = 0; j_ < 2; ++j_){                                            \
        int br = wn*32 + j_*16 + (lane & 15);                                    \
        int ch = (kc ^ ((br >> 1) & 3)) & 3;                                     \
        bb[j_] = *(const bf16x8*)&Bs[(J)&1][br*32 + ch*8];                       \
      }                                                                          \
      _Pragma("unroll")                                                          \
      for (int i_ = 0; i_ < 4; ++i_)                                             \
        _Pragma("unroll")                                                        \
        for (int j_ = 0; j_ < 2; ++j_)                                           \
          acc[i_][j_] = __builtin_amdgcn_mfma_f32_16x16x32_bf16(af[i_], bb[j_], acc[i_][j_], 0,0,0); \
    }                                                                            \
  }

// prologue: load B(0),B(1) + A(0),A(1); write Bs[0]<-B(0)
#define GEMM_PROLOGUE()                                                          \
  {                                                                              \
    rb0a = *(const f2*)(bbase);                                                  \
    rb0b = *(const f2*)(bbase + (size_t)N);                                      \
    gld_lds16(asrc0, &As[0][tid*8]);                                             \
    gld_lds16(asrc1, &As[0][4096 + tid*8]);                                      \
    const float* bp_ = bbase + (size_t)32 * N;                                   \
    rb1a = *(const f2*)(bp_);                                                    \
    rb1b = *(const f2*)(bp_ + (size_t)N);                                        \
    gld_lds16(asrc0 + 32, &As[1][tid*8]);                                        \
    gld_lds16(asrc1 + 32, &As[1][4096 + tid*8]);                                 \
    uint_t pk0 = f2bf(rb0a[0]) | ((uint_t)f2bf(rb0b[0]) << 16);                  \
    uint_t pk1 = f2bf(rb0a[1]) | ((uint_t)f2bf(rb0b[1]) << 16);                  \
    *(uint_t*)&Bs[0][bdoff0] = pk0;                                              \
    *(uint_t*)&Bs[0][bdoff1] = pk1;                                              \
  }

// gsrc==null: H = acc (bf16). gsrc!=null: H = silu(gsrc)*acc (bf16).
__global__ __launch_bounds__(512, 4) void gemm_xw_kernel(
    const ushort_t* __restrict__ A, const float* __restrict__ B0,
    const ushort_t* __restrict__ gsrc, ushort_t* __restrict__ H,
    const int* __restrict__ offsets, const int* __restrict__ row_token,
    const ushort_t* __restrict__ zerop,
    int N, int K, int lda, int n_mt, int n_nt, int Mfix)
{
  int nwg = gridDim.x, chunk = nwg >> 3;
  int L = (blockIdx.x & 7)*chunk + (blockIdx.x >> 3);
  int e, mt, nt, row0, rowcnt;
  if (offsets){
    int per = n_mt*n_nt; e = L/per; int rem = L - e*per; mt = rem/n_nt; nt = rem - mt*n_nt;
    row0 = offsets[e]; rowcnt = offsets[e+1] - row0;
  } else { e = 0; nt = L/n_mt; mt = L - nt*n_mt; row0 = 0; rowcnt = Mfix; }
  int m0 = mt*256;
  if (m0 >= rowcnt) return;

  const float* B = B0 + (size_t)e*K*N + nt*64;

  __shared__ ushort_t As[4][8192];   // 4 bufs x 16KB (256r x 32k bf16)
  __shared__ ushort_t Bs[2][2048];   // 2 bufs x 4KB  (64n x 32k bf16)

  int tid = threadIdx.x;
  int lane = tid & 63;
  int wid = tid >> 6;
  int wm = wid >> 1, wn = wid & 1;

  // A sources (gathered rows, pre-swizzled source chunk; verified r7)
  int sslot = (tid & 3) ^ ((tid >> 3) & 3);
  const ushort_t *asrc0, *asrc1;
  {
    int r0 = (tid >> 2), r1 = (tid >> 2) + 128;
    int g0 = m0 + r0, g1 = m0 + r1;
    bool v0 = g0 < rowcnt, v1 = g1 < rowcnt;
    int tk0 = row_token ? (v0 ? row_token[row0+g0] : 0) : g0;
    int tk1 = row_token ? (v1 ? row_token[row0+g1] : 0) : g1;
    asrc0 = (v0 ? (A + (size_t)tk0*lda) : zerop) + sslot*8;
    asrc1 = (v1 ? (A + (size_t)tk1*lda) : zerop) + sslot*8;
  }

  // B staging mapping (verified r7): thread -> cols 2n2,2n2+1 at k-rows 2k2,2k2+1
  int n2 = tid & 31, k2 = tid >> 5;
  const float* bbase = B + (size_t)(k2*2)*N + n2*2;
  int bdoff0, bdoff1;
  { int n = n2*2;     int slot = ((k2>>2) ^ ((n>>1)&3)) & 3; bdoff0 = n*32 + slot*8 + (k2&3)*2; }
  { int n = n2*2 + 1; int slot = ((k2>>2) ^ ((n>>1)&3)) & 3; bdoff1 = n*32 + slot*8 + (k2&3)*2; }

  f32x4 acc[4][2];
  #pragma unroll
  for (int i=0;i<4;++i)
    #pragma unroll
    for (int j=0;j<2;++j) acc[i][j] = f32x4{0.f,0.f,0.f,0.f};

  int nK = K >> 5;
  f2 rb0a, rb0b, rb1a, rb1b;
  GEMM_PROLOGUE();

  for (int base = 0; base < nK; base += 4){
    GEMM_STEP(0, rb1a, rb1b, rb0a, rb0b)
    GEMM_STEP(1, rb0a, rb0b, rb1a, rb1b)
    GEMM_STEP(2, rb1a, rb1b, rb0a, rb0b)
    GEMM_STEP(3, rb0a, rb0b, rb1a, rb1b)
  }

  #pragma unroll
  for (int i = 0; i < 4; ++i)
    #pragma unroll
    for (int j = 0; j < 2; ++j){
      int col = nt*64 + wn*32 + j*16 + (lane & 15);
      #pragma unroll
      for (int q = 0; q < 4; ++q){
        int r = wm*64 + i*16 + ((lane >> 4) << 2) + q;
        int gr = m0 + r;
        if (gr < rowcnt){
          float val = acc[i][j][q];
          size_t idx = (size_t)(row0 + gr)*(size_t)N + col;
          if (gsrc){
            float g = bf2f(gsrc[idx]);
            val = (g / (1.f + __expf(-g))) * val;
          }
          H[idx] = f2bf(val);
        }
      }
    }
}

// ---------- down GEMM: same core; routed -> weighted bf16 rows; shared -> f32 out ----------
__global__ __launch_bounds__(512, 4) void gemm_down_kernel(
    const ushort_t* __restrict__ A, const float* __restrict__ B0,
    ushort_t* __restrict__ outb, float* __restrict__ outf,
    const int* __restrict__ offsets, const float* __restrict__ row_w, const int* __restrict__ row_assign,
    const ushort_t* __restrict__ zerop,
    int N, int K, int lda, int n_mt, int n_nt, int Mfix)
{
  int nwg = gridDim.x, chunk = nwg >> 3;
  int L = (blockIdx.x & 7)*chunk + (blockIdx.x >> 3);
  int e, mt, nt, row0, rowcnt;
  if (offsets){
    int per = n_mt*n_nt; e = L/per; int rem = L - e*per; mt = rem/n_nt; nt = rem - mt*n_nt;
    row0 = offsets[e]; rowcnt = offsets[e+1] - row0;
  } else { e = 0; nt = L/n_mt; mt = L - nt*n_mt; row0 = 0; rowcnt = Mfix; }
  int m0 = mt*256;
  if (m0 >= rowcnt) return;

  const float* B = B0 + (size_t)e*K*N + nt*64;

  __shared__ ushort_t As[4][8192];
  __shared__ ushort_t Bs[2][2048];
  __shared__ float Wr[256];
  __shared__ int Ar[256];

  int tid = threadIdx.x;
  int lane = tid & 63;
  int wid = tid >> 6;
  int wm = wid >> 1, wn = wid & 1;

  if (offsets && tid < 256){
    int gr = m0 + tid;
    bool v = gr < rowcnt;
    Wr[tid] = v ? row_w[row0+gr] : 0.f;
    Ar[tid] = v ? row_assign[row0+gr] : 0;
  }

  int sslot = (tid & 3) ^ ((tid >> 3) & 3);
  const ushort_t *asrc0, *asrc1;
  {
    int r0 = (tid >> 2), r1 = (tid >> 2) + 128;
    int g0 = m0 + r0, g1 = m0 + r1;
    bool v0 = g0 < rowcnt, v1 = g1 < rowcnt;
    asrc0 = (v0 ? (A + (size_t)(row0+g0)*lda) : zerop) + sslot*8;
    asrc1 = (v1 ? (A + (size_t)(row0+g1)*lda) : zerop) + sslot*8;
  }

  int n2 = tid & 31, k2 = tid >> 5;
  const float* bbase = B + (size_t)(k2*2)*N + n2*2;
  int bdoff0, bdoff1;
  { int n = n2*2;     int slot = ((k2>>2) ^ ((n>>1)&3)) & 3; bdoff0 = n*32 + slot*8 + (k2&3)*2; }
  { int n = n2*2 + 1; int slot = ((k2>>2) ^ ((n>>1)&3)) & 3; bdoff1 = n*32 + slot*8 + (k2&3)*2; }

  f32x4 acc[4][2];
  #pragma unroll
  for (int i=0;i<4;++i)
    #pragma unroll
    for (int j=0;j<2;++j) acc[i][j] = f32x4{0.f,0.f,0.f,0.f};

  int nK = K >> 5;
  f2 rb0a, rb0b, rb1a, rb1b;
  GEMM_PROLOGUE();

  for (int base = 0; base < nK; base += 4){
    GEMM_STEP(0, rb1a, rb1b, rb0a, rb0b)
    GEMM_STEP(1, rb0a, rb0b, rb1a, rb1b)
    GEMM_STEP(2, rb1a, rb1b, rb0a, rb0b)
    GEMM_STEP(3, rb0a, rb0b, rb1a, rb1b)
  }

  #pragma unroll
  for (int i = 0; i < 4; ++i)
    #pragma unroll
    for (int j = 0; j < 2; ++j){
      int col = nt*64 + wn*32 + j*16 + (lane & 15);
      #pragma unroll
      for (int q = 0; q < 4; ++q){
        int r = wm*64 + i*16 + ((lane >> 4) << 2) + q;
        int gr = m0 + r;
        if (gr < rowcnt){
          float val = acc[i][j][q];
          if (offsets){
            outb[(size_t)Ar[r]*2048 + col] = f2bf(val * Wr[r]);
          } else {
            outf[(size_t)gr*2048 + col] = val;
          }
        }
      }
    }
}

// ---------- combine: out += sum_k out_assign[t*6+k] ----------
__global__ __launch_bounds__(256) void combine_kernel(const ushort_t* __restrict__ oa, float* __restrict__ out){
  size_t base = ((size_t)blockIdx.x*256 + threadIdx.x)*8;
  int t = (int)(base >> 11);
  int d = (int)(base & 2047);
  f4 s0 = *(const f4*)(out + base);
  f4 s1 = *(const f4*)(out + base + 4);
  #pragma unroll
  for (int k = 0; k < 6; ++k){
    const ushort_t* row = oa + (((size_t)(t*6+k)) << 11) + d;
    uint4 u = *(const uint4*)row;
    s0.x += bf2f(u.x); s0.y += bf2f(u.x >> 16);
    s0.z += bf2f(u.y); s0.w += bf2f(u.y >> 16);
    s1.x += bf2f(u.z); s1.y += bf2f(u.z >> 16);
    s1.z += bf2f(u.w); s1.w += bf2f(u.w >> 16);
  }
  *(f4*)(out + base) = s0;
  *(f4*)(out + base + 4) = s1;
}

extern "C" void kernel_launch(void* const* d_in, const int* in_sizes, int n_in,
                              void* d_out, int out_size, void* d_ws, size_t ws_size,
                              hipStream_t stream)
{
  const float* x       = (const float*)d_in[0];
  const float* gate_w  = (const float*)d_in[1];
  const float* w_gate  = (const float*)d_in[2];
  const float* w_up    = (const float*)d_in[3];
  const float* w_down  = (const float*)d_in[4];
  const float* ws_gate = (const float*)d_in[5];
  const float* ws_up   = (const float*)d_in[6];
  const float* ws_down = (const float*)d_in[7];
  float* out = (float*)d_out;

  char* ws = (char*)d_ws;
  int*      topi       = (int*)(ws + 0);           // 49152
  float*    topw       = (float*)(ws + 49152);     // 49152
  int*      counts     = (int*)(ws + 98304);       // 256
  int*      cursor     = (int*)(ws + 98560);       // 256
  int*      offsets    = (int*)(ws + 98816);       // 512
  int*      row_token  = (int*)(ws + 99328);       // 49152
  float*    row_w      = (float*)(ws + 148480);    // 49152
  int*      row_assign = (int*)(ws + 197632);      // 49152
  ushort_t* zerop      = (ushort_t*)(ws + 262144); // 8192B zeros
  ushort_t* xb         = (ushort_t*)(ws + 524288);   // 8.39 MB
  ushort_t* Hbuf       = (ushort_t*)(ws + 8912896);  // 34.6 MB  [12288 x 1408] bf16
  ushort_t* Shbuf      = (ushort_t*)(ws + 43515904); // 11.5 MB  [2048 x 2816] bf16
  ushort_t* oa         = (ushort_t*)(ws + 55050240); // 50.3 MB  [12288 x 2048] bf16
  // G buffers alias oa (dead before routed-down writes oa)
  ushort_t* Gbuf = oa;                                          // 34.6 MB [12288 x 1408]
  ushort_t* GS   = (ushort_t*)(ws + 55050240 + 34603008);       // 11.5 MB [2048 x 2816]
  (void)ws_size; (void)in_sizes; (void)n_in; (void)out_size;

  hipMemsetAsync(ws + 98304, 0, 512, stream);     // counts + cursor
  hipMemsetAsync(zerop, 0, 8192, stream);

  gate_topk_kernel<<<512, 256, 0, stream>>>(x, gate_w, topi, topw);
  xcast_kernel<<<2048, 256, 0, stream>>>(x, xb);
  count_kernel<<<48, 256, 0, stream>>>(topi, counts);
  scan_kernel<<<1, 64, 0, stream>>>(counts, offsets);
  scatter_kernel<<<48, 256, 0, stream>>>(topi, topw, offsets, cursor, row_token, row_w, row_assign);

  // routed gate: 64e x 2mt x 22nt -> Gbuf
  gemm_xw_kernel<<<2816, 512, 0, stream>>>(xb, w_gate, nullptr, Gbuf, offsets, row_token, zerop,
                                           FDIM, DDIM, DDIM, 2, 22, 0);
  // shared gate: 8mt x 44nt -> GS
  gemm_xw_kernel<<<352, 512, 0, stream>>>(xb, ws_gate, nullptr, GS, nullptr, nullptr, zerop,
                                          FSH, DDIM, DDIM, 8, 44, TTOK);
  // routed up (+silu combine): -> Hbuf
  gemm_xw_kernel<<<2816, 512, 0, stream>>>(xb, w_up, Gbuf, Hbuf, offsets, row_token, zerop,
                                           FDIM, DDIM, DDIM, 2, 22, 0);
  // shared up (+silu combine): -> Shbuf
  gemm_xw_kernel<<<352, 512, 0, stream>>>(xb, ws_up, GS, Shbuf, nullptr, nullptr, zerop,
                                          FSH, DDIM, DDIM, 8, 44, TTOK);
  // shared down -> d_out (f32)
  gemm_down_kernel<<<256, 512, 0, stream>>>(Shbuf, ws_down, nullptr, out, nullptr, nullptr, nullptr, zerop,
                                            DDIM, FSH, FSH, 8, 32, TTOK);
  // routed down -> weighted bf16 per-assignment rows (overwrites dead G region)
  gemm_down_kernel<<<4096, 512, 0, stream>>>(Hbuf, w_down, oa, nullptr, offsets, row_w, row_assign, zerop,
                                             DDIM, FDIM, FDIM, 2, 32, 0);
  // combine: out += sum of 6 assignment rows
  combine_kernel<<<2048, 256, 0, stream>>>(oa, out);
}

// Round 9
// 1045.725 us; speedup vs baseline: 1.2351x; 1.1825x over previous
//
#include <hip/hip_runtime.h>
#include <hip/hip_bf16.h>
#include <cstdint>

typedef __attribute__((ext_vector_type(4))) float f4;
typedef __attribute__((ext_vector_type(4))) float f32x4;
typedef __attribute__((ext_vector_type(8))) __bf16 bf16x8;
typedef unsigned short ushort_t;
typedef unsigned int uint_t;

#define TTOK 2048
#define DDIM 2048
#define NEXP 64
#define TOPK 6
#define FDIM 1408
#define FSH  2816
#define NASSIGN (TTOK*TOPK)

#define SBAR()     __asm__ __volatile__("s_barrier" ::: "memory")
#define WAITVMC(N) __asm__ __volatile__("s_waitcnt vmcnt(" #N ")" ::: "memory")
#define WAITLG()   __asm__ __volatile__("s_waitcnt lgkmcnt(0)" ::: "memory")

// ---------- helpers ----------
__device__ __forceinline__ ushort_t f2bf(float f){
  uint_t u = __builtin_bit_cast(uint_t, f);
  u = (u + 0x7FFFu + ((u >> 16) & 1u)) >> 16;
  return (ushort_t)u;
}
__device__ __forceinline__ float bf2f(uint_t b){
  uint_t u = (b & 0xFFFFu) << 16;
  return __builtin_bit_cast(float, u);
}
__device__ __forceinline__ void gld_lds16(const void* g, void* l){
  __builtin_amdgcn_global_load_lds((const __attribute__((address_space(1))) uint_t*)g,
                                   (__attribute__((address_space(3))) uint_t*)l, 16, 0, 0);
}

// ---------- gate: logits + top-6 + renorm ----------
__global__ __launch_bounds__(256) void gate_topk_kernel(
    const float* __restrict__ x, const float* __restrict__ gw,
    int* __restrict__ topi, float* __restrict__ topw)
{
  __shared__ float xs[4*2048];
  __shared__ float lg[4*64];
  int tid = threadIdx.x;
  int t0 = blockIdx.x*4;
  const f4* xg = (const f4*)(x + (size_t)t0*DDIM);
  f4* xsv = (f4*)xs;
  for (int i = tid; i < 2048; i += 256) xsv[i] = xg[i];
  __syncthreads();
  int g = tid >> 6, l = tid & 63;
  int c = l & 3, er = l >> 2;
  const f4* xrow = (const f4*)(xs + g*2048 + c*512);
  #pragma unroll
  for (int eo = 0; eo < 4; ++eo){
    int e = eo*16 + er;
    const f4* wrow = (const f4*)(gw + (size_t)e*DDIM + c*512);
    float d = 0.f;
    #pragma unroll 4
    for (int j = 0; j < 128; ++j){
      f4 w = wrow[j], a = xrow[j];
      d += w.x*a.x + w.y*a.y + w.z*a.z + w.w*a.w;
    }
    d += __shfl_xor(d, 1);
    d += __shfl_xor(d, 2);
    if (c == 0) lg[g*64 + e] = d;
  }
  __syncthreads();
  float mv = lg[g*64 + l];
  float sv[6]; int si[6];
  #pragma unroll
  for (int s = 0; s < 6; ++s){
    float bv = mv; int bi = l;
    for (int off = 32; off > 0; off >>= 1){
      float ov = __shfl_xor(bv, off);
      int oi = __shfl_xor(bi, off);
      if (ov > bv || (ov == bv && oi < bi)){ bv = ov; bi = oi; }
    }
    sv[s] = bv; si[s] = bi;
    if (l == bi) mv = -3.4e38f;
  }
  if (l == 0){
    float sum = 0.f, wv[6];
    #pragma unroll
    for (int s = 0; s < 6; ++s){ wv[s] = __expf(sv[s] - sv[0]); sum += wv[s]; }
    float inv = 1.f/sum;
    int t = t0 + g;
    #pragma unroll
    for (int s = 0; s < 6; ++s){ topi[t*6+s] = si[s]; topw[t*6+s] = wv[s]*inv; }
  }
}

// ---------- x -> bf16 ----------
__global__ __launch_bounds__(256) void xcast_kernel(const float* __restrict__ x, ushort_t* __restrict__ xb){
  size_t base = ((size_t)blockIdx.x*256 + threadIdx.x)*8;
  f4 a = *(const f4*)(x + base);
  f4 b = *(const f4*)(x + base + 4);
  uint4 r;
  r.x = f2bf(a.x) | ((uint_t)f2bf(a.y)<<16);
  r.y = f2bf(a.z) | ((uint_t)f2bf(a.w)<<16);
  r.z = f2bf(b.x) | ((uint_t)f2bf(b.y)<<16);
  r.w = f2bf(b.z) | ((uint_t)f2bf(b.w)<<16);
  *(uint4*)(xb + base) = r;
}

// ---------- routing bookkeeping ----------
__global__ __launch_bounds__(256) void count_kernel(const int* __restrict__ topi, int* __restrict__ counts){
  int a = blockIdx.x*256 + threadIdx.x;
  if (a < NASSIGN) atomicAdd(&counts[topi[a]], 1);
}
__global__ void scan_kernel(const int* __restrict__ counts, int* __restrict__ offsets){
  if (threadIdx.x == 0){
    int s = 0;
    for (int e = 0; e < NEXP; ++e){ offsets[e] = s; s += counts[e]; }
    offsets[NEXP] = s;
  }
}
__global__ __launch_bounds__(256) void scatter_kernel(
    const int* __restrict__ topi, const float* __restrict__ topw,
    const int* __restrict__ offsets, int* __restrict__ cursor,
    int* __restrict__ row_token, float* __restrict__ row_w, int* __restrict__ row_assign)
{
  int a = blockIdx.x*256 + threadIdx.x;
  if (a < NASSIGN){
    int e = topi[a];
    int pos = atomicAdd(&cursor[e], 1);
    int r = offsets[e] + pos;
    row_token[r]  = a / 6;
    row_w[r]      = topw[a];
    row_assign[r] = a;
  }
}

// ====== fused gate+up GEMM (+silu*mul): BM=256 BN=64(each) BK=32, 512 thr (8 waves 4m x 2n) ======
// A: gld_lds dbuf. B: per-thread column ownership, 4 scalar loads/matrix, ds_write_b64 into
// [kchunk][n] layout (conflict-free). r4 counted-vmcnt schedule. LDS 40KB -> 4 blk/CU.
__global__ __launch_bounds__(512, 4) void gemm_gateup_kernel(
    const ushort_t* __restrict__ A, const float* __restrict__ Bg0, const float* __restrict__ Bu0,
    ushort_t* __restrict__ H,
    const int* __restrict__ offsets, const int* __restrict__ row_token,
    const ushort_t* __restrict__ zerop,
    int N, int K, int lda, int n_mt, int n_nt, int Mfix)
{
  int nwg = gridDim.x, chunk = nwg >> 3;
  int L = (blockIdx.x & 7)*chunk + (blockIdx.x >> 3);
  int e, mt, nt, row0, rowcnt;
  if (offsets){
    int per = n_mt*n_nt; e = L/per; int rem = L - e*per; mt = rem/n_nt; nt = rem - mt*n_nt;
    row0 = offsets[e]; rowcnt = offsets[e+1] - row0;
  } else { e = 0; nt = L/n_mt; mt = L - nt*n_mt; row0 = 0; rowcnt = Mfix; }
  int m0 = mt*256;
  if (m0 >= rowcnt) return;

  __shared__ ushort_t As[2][8192];   // A dbuf: 256r x 32k bf16, 16KB each
  __shared__ ushort_t Bsh[2][2048];  // [mat][kc*512 + n*8 + koff]: 64n x 32k bf16, 4KB each

  int tid = threadIdx.x;
  int lane = tid & 63;
  int wid = tid >> 6;
  int wm = wid >> 1, wn = wid & 1;

  // A sources: row r = (tid>>2)+128i, chunk (tid&3); linear LDS dst = tid*8 (+i*4096)
  const ushort_t *asrc0, *asrc1;
  {
    int r0 = (tid >> 2), r1 = r0 + 128;
    int g0 = m0 + r0, g1 = m0 + r1;
    bool v0 = g0 < rowcnt, v1 = g1 < rowcnt;
    int tk0 = row_token ? (v0 ? row_token[row0+g0] : 0) : g0;
    int tk1 = row_token ? (v1 ? row_token[row0+g1] : 0) : g1;
    asrc0 = (v0 ? (A + (size_t)tk0*lda) : zerop) + (tid & 3)*8;
    asrc1 = (v1 ? (A + (size_t)tk1*lda) : zerop) + (tid & 3)*8;
  }

  // B: thread owns col bn (0..63) at k-rows k4*4..+3
  int bn = tid & 63, k4 = tid >> 6;
  const float* bgp = Bg0 + (size_t)e*K*N + nt*64 + bn;
  const float* bup = Bu0 + (size_t)e*K*N + nt*64 + bn;
  int bwoff = (k4 >> 1)*512 + bn*8 + (k4 & 1)*4;   // ushort index

  f32x4 accG[4][2], accU[4][2];
  #pragma unroll
  for (int i=0;i<4;++i)
    #pragma unroll
    for (int j=0;j<2;++j){ accG[i][j] = f32x4{0.f,0.f,0.f,0.f}; accU[i][j] = f32x4{0.f,0.f,0.f,0.f}; }

  int nK = K >> 5;
  float g0,g1,g2,g3,u0,u1,u2,u3;
  // ---- prologue: B(0) scalar loads, A(0) glds, write B(0), drain lgkm ----
  {
    size_t kb = (size_t)(k4*4)*N;
    g0 = bgp[kb]; g1 = bgp[kb+N]; g2 = bgp[kb+2*(size_t)N]; g3 = bgp[kb+3*(size_t)N];
    u0 = bup[kb]; u1 = bup[kb+N]; u2 = bup[kb+2*(size_t)N]; u3 = bup[kb+3*(size_t)N];
    gld_lds16(asrc0, &As[0][tid*8]);
    gld_lds16(asrc1, &As[0][4096 + tid*8]);
    uint2 pg; pg.x = f2bf(g0) | ((uint_t)f2bf(g1)<<16); pg.y = f2bf(g2) | ((uint_t)f2bf(g3)<<16);
    uint2 pu; pu.x = f2bf(u0) | ((uint_t)f2bf(u1)<<16); pu.y = f2bf(u2) | ((uint_t)f2bf(u3)<<16);
    *(uint2*)&Bsh[0][bwoff] = pg;
    *(uint2*)&Bsh[1][bwoff] = pu;
    WAITLG();
  }

  for (int ks = 0; ks < nK; ++ks){
    int cur = ks & 1, nxt = cur ^ 1;
    bool pf = (ks + 1) < nK;
    if (pf){
      size_t kb = (size_t)(((ks+1) << 5) + k4*4)*N;
      g0 = bgp[kb]; g1 = bgp[kb+N]; g2 = bgp[kb+2*(size_t)N]; g3 = bgp[kb+3*(size_t)N];
      u0 = bup[kb]; u1 = bup[kb+N]; u2 = bup[kb+2*(size_t)N]; u3 = bup[kb+3*(size_t)N];
      int k0n = (ks + 1) << 5;
      gld_lds16(asrc0 + k0n, &As[nxt][tid*8]);
      gld_lds16(asrc1 + k0n, &As[nxt][4096 + tid*8]);
      WAITVMC(10);       // drain A(ks)[2]; keep B(ks+1)[8]+A(ks+1)[2] in flight
    } else {
      WAITVMC(0);
    }
    SBAR();              // A(ks) ready; B(ks) visible

    {
      int kc = lane >> 4;
      bf16x8 af[4], bg[2], bu[2];
      #pragma unroll
      for (int i = 0; i < 4; ++i){
        int ar = wm*64 + i*16 + (lane & 15);
        af[i] = *(const bf16x8*)&As[cur][ar*32 + kc*8];
      }
      #pragma unroll
      for (int j = 0; j < 2; ++j){
        int br = wn*32 + j*16 + (lane & 15);
        bg[j] = *(const bf16x8*)&Bsh[0][kc*512 + br*8];
        bu[j] = *(const bf16x8*)&Bsh[1][kc*512 + br*8];
      }
      #pragma unroll
      for (int i = 0; i < 4; ++i)
        #pragma unroll
        for (int j = 0; j < 2; ++j){
          accG[i][j] = __builtin_amdgcn_mfma_f32_16x16x32_bf16(af[i], bg[j], accG[i][j], 0,0,0);
          accU[i][j] = __builtin_amdgcn_mfma_f32_16x16x32_bf16(af[i], bu[j], accU[i][j], 0,0,0);
        }
    }
    SBAR();              // all waves done reading Bsh
    if (pf){
      uint2 pg; pg.x = f2bf(g0) | ((uint_t)f2bf(g1)<<16); pg.y = f2bf(g2) | ((uint_t)f2bf(g3)<<16);
      uint2 pu; pu.x = f2bf(u0) | ((uint_t)f2bf(u1)<<16); pu.y = f2bf(u2) | ((uint_t)f2bf(u3)<<16);
      *(uint2*)&Bsh[0][bwoff] = pg;
      *(uint2*)&Bsh[1][bwoff] = pu;
      WAITLG();
    }
  }

  #pragma unroll
  for (int i = 0; i < 4; ++i)
    #pragma unroll
    for (int j = 0; j < 2; ++j){
      int col = nt*64 + wn*32 + j*16 + (lane & 15);
      #pragma unroll
      for (int q = 0; q < 4; ++q){
        int r = wm*64 + i*16 + ((lane >> 4) << 2) + q;
        int gr = m0 + r;
        if (gr < rowcnt){
          float gv = accG[i][j][q];
          float uv = accU[i][j][q];
          float hv = (gv / (1.f + __expf(-gv))) * uv;
          H[(size_t)(row0 + gr)*(size_t)N + col] = f2bf(hv);
        }
      }
    }
}

// ====== down GEMM: BM=256 BN=128 BK=32, 512 thr (8 waves 4m x 2n, wave 64x64) ======
__global__ __launch_bounds__(512, 4) void gemm_down_kernel(
    const ushort_t* __restrict__ A, const float* __restrict__ B0,
    ushort_t* __restrict__ outb, float* __restrict__ outf,
    const int* __restrict__ offsets, const float* __restrict__ row_w, const int* __restrict__ row_assign,
    const ushort_t* __restrict__ zerop,
    int N, int K, int lda, int n_mt, int n_nt, int Mfix)
{
  int nwg = gridDim.x, chunk = nwg >> 3;
  int L = (blockIdx.x & 7)*chunk + (blockIdx.x >> 3);
  int e, mt, nt, row0, rowcnt;
  if (offsets){
    int per = n_mt*n_nt; e = L/per; int rem = L - e*per; mt = rem/n_nt; nt = rem - mt*n_nt;
    row0 = offsets[e]; rowcnt = offsets[e+1] - row0;
  } else { e = 0; nt = L/n_mt; mt = L - nt*n_mt; row0 = 0; rowcnt = Mfix; }
  int m0 = mt*256;
  if (m0 >= rowcnt) return;

  __shared__ ushort_t As[2][8192];   // 16KB each
  __shared__ ushort_t Bs[4096];      // [kc*1024 + n*8]: 128n x 32k bf16, 8KB
  __shared__ float Wr[256];
  __shared__ int Ar[256];

  int tid = threadIdx.x;
  int lane = tid & 63;
  int wid = tid >> 6;
  int wm = wid >> 1, wn = wid & 1;

  if (offsets && tid < 256){
    int gr = m0 + tid;
    bool v = gr < rowcnt;
    Wr[tid] = v ? row_w[row0+gr] : 0.f;
    Ar[tid] = v ? row_assign[row0+gr] : 0;
  }

  const ushort_t *asrc0, *asrc1;
  {
    int r0 = (tid >> 2), r1 = r0 + 128;
    int g0 = m0 + r0, g1 = m0 + r1;
    bool v0 = g0 < rowcnt, v1 = g1 < rowcnt;
    asrc0 = (v0 ? (A + (size_t)(row0+g0)*lda) : zerop) + (tid & 3)*8;
    asrc1 = (v1 ? (A + (size_t)(row0+g1)*lda) : zerop) + (tid & 3)*8;
  }

  // B: thread owns col bn (0..127) at k-rows k8*8..+7
  int bn = tid & 127, k8 = tid >> 7;
  const float* bp = B0 + (size_t)e*K*N + nt*128 + bn;
  int bwoff = k8*1024 + bn*8;   // ushort index (16B aligned)

  f32x4 acc[4][4];
  #pragma unroll
  for (int i=0;i<4;++i)
    #pragma unroll
    for (int j=0;j<4;++j) acc[i][j] = f32x4{0.f,0.f,0.f,0.f};

  int nK = K >> 5;
  float b0,b1,b2,b3,b4,b5,b6,b7;
  {
    size_t kb = (size_t)(k8*8)*N;
    b0=bp[kb]; b1=bp[kb+N]; b2=bp[kb+2*(size_t)N]; b3=bp[kb+3*(size_t)N];
    b4=bp[kb+4*(size_t)N]; b5=bp[kb+5*(size_t)N]; b6=bp[kb+6*(size_t)N]; b7=bp[kb+7*(size_t)N];
    gld_lds16(asrc0, &As[0][tid*8]);
    gld_lds16(asrc1, &As[0][4096 + tid*8]);
    uint4 pk;
    pk.x = f2bf(b0) | ((uint_t)f2bf(b1)<<16);
    pk.y = f2bf(b2) | ((uint_t)f2bf(b3)<<16);
    pk.z = f2bf(b4) | ((uint_t)f2bf(b5)<<16);
    pk.w = f2bf(b6) | ((uint_t)f2bf(b7)<<16);
    *(uint4*)&Bs[bwoff] = pk;
    WAITLG();
  }

  for (int ks = 0; ks < nK; ++ks){
    int cur = ks & 1, nxt = cur ^ 1;
    bool pf = (ks + 1) < nK;
    if (pf){
      size_t kb = (size_t)(((ks+1) << 5) + k8*8)*N;
      b0=bp[kb]; b1=bp[kb+N]; b2=bp[kb+2*(size_t)N]; b3=bp[kb+3*(size_t)N];
      b4=bp[kb+4*(size_t)N]; b5=bp[kb+5*(size_t)N]; b6=bp[kb+6*(size_t)N]; b7=bp[kb+7*(size_t)N];
      int k0n = (ks + 1) << 5;
      gld_lds16(asrc0 + k0n, &As[nxt][tid*8]);
      gld_lds16(asrc1 + k0n, &As[nxt][4096 + tid*8]);
      WAITVMC(10);       // drain A(ks)[2]; keep B(ks+1)[8]+A(ks+1)[2]
    } else {
      WAITVMC(0);
    }
    SBAR();

    {
      int kc = lane >> 4;
      bf16x8 af[4], bb[4];
      #pragma unroll
      for (int i = 0; i < 4; ++i){
        int ar = wm*64 + i*16 + (lane & 15);
        af[i] = *(const bf16x8*)&As[cur][ar*32 + kc*8];
      }
      #pragma unroll
      for (int j = 0; j < 4; ++j){
        int br = wn*64 + j*16 + (lane & 15);
        bb[j] = *(const bf16x8*)&Bs[kc*1024 + br*8];
      }
      #pragma unroll
      for (int i = 0; i < 4; ++i)
        #pragma unroll
        for (int j = 0; j < 4; ++j)
          acc[i][j] = __builtin_amdgcn_mfma_f32_16x16x32_bf16(af[i], bb[j], acc[i][j], 0,0,0);
    }
    SBAR();
    if (pf){
      uint4 pk;
      pk.x = f2bf(b0) | ((uint_t)f2bf(b1)<<16);
      pk.y = f2bf(b2) | ((uint_t)f2bf(b3)<<16);
      pk.z = f2bf(b4) | ((uint_t)f2bf(b5)<<16);
      pk.w = f2bf(b6) | ((uint_t)f2bf(b7)<<16);
      *(uint4*)&Bs[bwoff] = pk;
      WAITLG();
    }
  }

  #pragma unroll
  for (int i = 0; i < 4; ++i)
    #pragma unroll
    for (int j = 0; j < 4; ++j){
      int col = nt*128 + wn*64 + j*16 + (lane & 15);
      #pragma unroll
      for (int q = 0; q < 4; ++q){
        int r = wm*64 + i*16 + ((lane >> 4) << 2) + q;
        int gr = m0 + r;
        if (gr < rowcnt){
          float val = acc[i][j][q];
          if (offsets){
            outb[(size_t)Ar[r]*2048 + col] = f2bf(val * Wr[r]);
          } else {
            outf[(size_t)gr*2048 + col] = val;
          }
        }
      }
    }
}

// ---------- combine: out += sum_k out_assign[t*6+k] ----------
__global__ __launch_bounds__(256) void combine_kernel(const ushort_t* __restrict__ oa, float* __restrict__ out){
  size_t base = ((size_t)blockIdx.x*256 + threadIdx.x)*8;
  int t = (int)(base >> 11);
  int d = (int)(base & 2047);
  f4 s0 = *(const f4*)(out + base);
  f4 s1 = *(const f4*)(out + base + 4);
  #pragma unroll
  for (int k = 0; k < 6; ++k){
    const ushort_t* row = oa + (((size_t)(t*6+k)) << 11) + d;
    uint4 u = *(const uint4*)row;
    s0.x += bf2f(u.x); s0.y += bf2f(u.x >> 16);
    s0.z += bf2f(u.y); s0.w += bf2f(u.y >> 16);
    s1.x += bf2f(u.z); s1.y += bf2f(u.z >> 16);
    s1.z += bf2f(u.w); s1.w += bf2f(u.w >> 16);
  }
  *(f4*)(out + base) = s0;
  *(f4*)(out + base + 4) = s1;
}

extern "C" void kernel_launch(void* const* d_in, const int* in_sizes, int n_in,
                              void* d_out, int out_size, void* d_ws, size_t ws_size,
                              hipStream_t stream)
{
  const float* x       = (const float*)d_in[0];
  const float* gate_w  = (const float*)d_in[1];
  const float* w_gate  = (const float*)d_in[2];
  const float* w_up    = (const float*)d_in[3];
  const float* w_down  = (const float*)d_in[4];
  const float* ws_gate = (const float*)d_in[5];
  const float* ws_up   = (const float*)d_in[6];
  const float* ws_down = (const float*)d_in[7];
  float* out = (float*)d_out;

  char* ws = (char*)d_ws;
  int*      topi       = (int*)(ws + 0);           // 49152
  float*    topw       = (float*)(ws + 49152);     // 49152
  int*      counts     = (int*)(ws + 98304);       // 256
  int*      cursor     = (int*)(ws + 98560);       // 256
  int*      offsets    = (int*)(ws + 98816);       // 512
  int*      row_token  = (int*)(ws + 99328);       // 49152
  float*    row_w      = (float*)(ws + 148480);    // 49152
  int*      row_assign = (int*)(ws + 197632);      // 49152
  ushort_t* zerop      = (ushort_t*)(ws + 262144); // 8192B zeros
  ushort_t* xb         = (ushort_t*)(ws + 524288);   // 8.39 MB
  ushort_t* Hbuf       = (ushort_t*)(ws + 8912896);  // 34.6 MB  [12288 x 1408] bf16
  ushort_t* Shbuf      = (ushort_t*)(ws + 43515904); // 11.5 MB  [2048 x 2816] bf16
  ushort_t* oa         = (ushort_t*)(ws + 55050240); // 50.3 MB  [12288 x 2048] bf16
  (void)ws_size; (void)in_sizes; (void)n_in; (void)out_size;

  hipMemsetAsync(ws + 98304, 0, 512, stream);     // counts + cursor
  hipMemsetAsync(zerop, 0, 8192, stream);

  gate_topk_kernel<<<512, 256, 0, stream>>>(x, gate_w, topi, topw);
  xcast_kernel<<<2048, 256, 0, stream>>>(x, xb);
  count_kernel<<<48, 256, 0, stream>>>(topi, counts);
  scan_kernel<<<1, 64, 0, stream>>>(counts, offsets);
  scatter_kernel<<<48, 256, 0, stream>>>(topi, topw, offsets, cursor, row_token, row_w, row_assign);

  // routed gate+up fused: 64e x 2mt x 22nt -> Hbuf
  gemm_gateup_kernel<<<2816, 512, 0, stream>>>(xb, w_gate, w_up, Hbuf, offsets, row_token, zerop,
                                               FDIM, DDIM, DDIM, 2, 22, 0);
  // shared gate+up fused: 8mt x 44nt -> Shbuf
  gemm_gateup_kernel<<<352, 512, 0, stream>>>(xb, ws_gate, ws_up, Shbuf, nullptr, nullptr, zerop,
                                              FSH, DDIM, DDIM, 8, 44, TTOK);
  // shared down -> d_out (f32): 8mt x 16nt
  gemm_down_kernel<<<128, 512, 0, stream>>>(Shbuf, ws_down, nullptr, out, nullptr, nullptr, nullptr, zerop,
                                            DDIM, FSH, FSH, 8, 16, TTOK);
  // routed down -> weighted bf16 per-assignment rows: 64e x 2mt x 16nt
  gemm_down_kernel<<<2048, 512, 0, stream>>>(Hbuf, w_down, oa, nullptr, offsets, row_w, row_assign, zerop,
                                             DDIM, FDIM, FDIM, 2, 16, 0);
  // combine: out += sum of 6 assignment rows
  combine_kernel<<<2048, 256, 0, stream>>>(oa, out);
}